// Round 2
// baseline (3481.499 us; speedup 1.0000x reference)
//
#include <hip/hip_runtime.h>

#define EPS 1e-5f
#define SLOPE 0.01f

// ===========================================================================
// Preprocessing: counting-sort edges by (output-range [, k]).
// S1: down pairs   key=(dst_down>>6)*27+k  rec = src | (dst&63)<<24
// S2: g pairs      key=(dst_g>>6)*27+k     rec = src | (dst&63)<<24
// S3: g transposed key=(src_g>>6)*27+k     rec = dst | (src&63)<<24
// S4: down transposed (for conv_up) key=src_down>>7
//     rec = dst_down | (src_down&127)<<16 | k<<23
// ===========================================================================
template<int WITHK>
__global__ __launch_bounds__(256) void hist_kernel(
    const int* __restrict__ scat, int E, int SH, int* __restrict__ cnt)
{
    const int k = blockIdx.y;
    const int* s = scat + (size_t)k * E;
    for (int e = blockIdx.x * 256 + threadIdx.x; e < E; e += gridDim.x * 256) {
        int key = s[e] >> SH;
        if (WITHK) key = key * 27 + k;
        atomicAdd(&cnt[key], 1);
    }
}

__global__ __launch_bounds__(1024) void scan_kernel(
    const int* __restrict__ cnt, int n, int* __restrict__ offs, int* __restrict__ cur)
{
    __shared__ int part[1024];
    const int tid = threadIdx.x;
    const int chunk = (n + 1023) >> 10;
    const int lo = tid * chunk, hi = min(n, lo + chunk);
    int s = 0;
    for (int i = lo; i < hi; ++i) s += cnt[i];
    part[tid] = s;
    __syncthreads();
    for (int d = 1; d < 1024; d <<= 1) {
        const int t = (tid >= d) ? part[tid - d] : 0;
        __syncthreads();
        part[tid] += t;
        __syncthreads();
    }
    int run = part[tid] - s;                 // exclusive prefix of this chunk
    for (int i = lo; i < hi; ++i) {
        const int cv = cnt[i];
        offs[i] = run; cur[i] = run; run += cv;
    }
    if (tid == 1023) offs[n] = run;          // total
}

template<int WITHK>
__global__ __launch_bounds__(256) void bucket_kernel(
    const int* __restrict__ gat, const int* __restrict__ scat, int E, int SH,
    int packSH, int kSH, int* __restrict__ cur, unsigned* __restrict__ recs)
{
    const int k = blockIdx.y;
    const int* g = gat + (size_t)k * E;
    const int* d = scat + (size_t)k * E;
    for (int e = blockIdx.x * 256 + threadIdx.x; e < E; e += gridDim.x * 256) {
        const int dv = d[e];
        int key = dv >> SH;
        if (WITHK) key = key * 27 + k;
        unsigned rec = (unsigned)g[e] | ((unsigned)(dv & ((1 << SH) - 1)) << packSH);
        if (!WITHK) rec |= (unsigned)k << kSH;
        const int pos = atomicAdd(&cur[key], 1);
        recs[pos] = rec;
    }
}

// ===========================================================================
// Gather conv: block owns 64 output rows in LDS, loops k staging W[k] in LDS.
// Scatter is conflict-free LDS atomic (lane = channel); each output row is
// written exactly once (no global atomics, no accumulator memset needed).
// ===========================================================================
template<int CIN>
__global__ __launch_bounds__(256) void conv_gather(
    const float* __restrict__ x, const float* __restrict__ W,
    const unsigned* __restrict__ recs, const int* __restrict__ offs,
    float* __restrict__ outb, int Nout)
{
    __shared__ float acc[64 * 64];          // 16 KB: 64 rows x 64 ch
    __shared__ float Wl[CIN * 64];          // 16/32 KB
    __shared__ float xl[4][4 * CIN];        // per-wave edge rows
    const int p   = blockIdx.x;
    const int tid = threadIdx.x;
    const int w   = tid >> 6;
    const int c   = tid & 63;

    const float4 z = {0.f, 0.f, 0.f, 0.f};
    for (int i = tid * 4; i < 64 * 64; i += 1024) *(float4*)&acc[i] = z;

    float* xw = xl[w];
    for (int k = 0; k < 27; ++k) {
        __syncthreads();                     // waves done with previous W
        const float* Wk = W + (size_t)k * (CIN * 64);
        for (int i = tid * 4; i < CIN * 64; i += 1024)
            *(float4*)&Wl[i] = *(const float4*)&Wk[i];
        __syncthreads();

        const int lo = offs[p * 27 + k], hi = offs[p * 27 + k + 1];
        for (int e0 = lo + w * 4; e0 < hi; e0 += 16) {
            const int ne = min(4, hi - e0);
            for (int j = 0; j < ne; ++j) {
                const unsigned r = recs[e0 + j];
                const int s = (int)(r & 0xFFFFFFu);
                #pragma unroll
                for (int h = 0; h < CIN / 64; ++h)
                    xw[j * CIN + h * 64 + c] = x[(size_t)s * CIN + h * 64 + c];
            }
            __builtin_amdgcn_wave_barrier();

            float a0 = 0.f, a1 = 0.f, a2 = 0.f, a3 = 0.f;
            #pragma unroll 4
            for (int i = 0; i < CIN; i += 4) {
                const float4 x0 = *(const float4*)&xw[0 * CIN + i];
                const float4 x1 = *(const float4*)&xw[1 * CIN + i];
                const float4 x2 = *(const float4*)&xw[2 * CIN + i];
                const float4 x3 = *(const float4*)&xw[3 * CIN + i];
                const float w0 = Wl[(i + 0) * 64 + c];
                const float w1 = Wl[(i + 1) * 64 + c];
                const float w2 = Wl[(i + 2) * 64 + c];
                const float w3 = Wl[(i + 3) * 64 + c];
                a0 = fmaf(x0.w, w3, fmaf(x0.z, w2, fmaf(x0.y, w1, fmaf(x0.x, w0, a0))));
                a1 = fmaf(x1.w, w3, fmaf(x1.z, w2, fmaf(x1.y, w1, fmaf(x1.x, w0, a1))));
                a2 = fmaf(x2.w, w3, fmaf(x2.z, w2, fmaf(x2.y, w1, fmaf(x2.x, w0, a2))));
                a3 = fmaf(x3.w, w3, fmaf(x3.z, w2, fmaf(x3.y, w1, fmaf(x3.x, w0, a3))));
            }
            __builtin_amdgcn_wave_barrier();

            if (ne > 0) atomicAdd(&acc[(int)(recs[e0 + 0] >> 24) * 64 + c], a0);
            if (ne > 1) atomicAdd(&acc[(int)(recs[e0 + 1] >> 24) * 64 + c], a1);
            if (ne > 2) atomicAdd(&acc[(int)(recs[e0 + 2] >> 24) * 64 + c], a2);
            if (ne > 3) atomicAdd(&acc[(int)(recs[e0 + 3] >> 24) * 64 + c], a3);
        }
    }
    __syncthreads();

    const int base = p * 64;
    for (int i = tid; i < 64 * 16; i += 256) {
        const int row = base + (i >> 4);
        if (row < Nout)
            *(float4*)&outb[(size_t)row * 64 + (i & 15) * 4] = *(const float4*)&acc[i * 4];
    }
}

// ---------------------------------------------------------------------------
// Cin=1 up-conv, gather-style: block owns 128 fine rows; all of W_up in LDS.
// ---------------------------------------------------------------------------
__global__ __launch_bounds__(256) void conv_up_gather(
    const float* __restrict__ s1, const float* __restrict__ Wup,
    const unsigned* __restrict__ recs, const int* __restrict__ offs,
    float* __restrict__ outb, int Nout)
{
    __shared__ float acc[128 * 64];          // 32 KB
    __shared__ float Wl[27 * 64];            // 6.9 KB
    const int p   = blockIdx.x;
    const int tid = threadIdx.x;
    const int w   = tid >> 6;
    const int c   = tid & 63;

    const float4 z = {0.f, 0.f, 0.f, 0.f};
    for (int i = tid * 4; i < 128 * 64; i += 1024) *(float4*)&acc[i] = z;
    for (int i = tid; i < 27 * 64; i += 256) Wl[i] = Wup[i];
    __syncthreads();

    const int lo = offs[p], hi = offs[p + 1];
    for (int e0 = lo + w * 4; e0 < hi; e0 += 16) {
        const int ne = min(4, hi - e0);
        if (ne > 0) { const unsigned r = recs[e0 + 0]; const float v = s1[r & 0xFFFFu];
                      atomicAdd(&acc[(int)((r >> 16) & 127u) * 64 + c], v * Wl[(int)(r >> 23) * 64 + c]); }
        if (ne > 1) { const unsigned r = recs[e0 + 1]; const float v = s1[r & 0xFFFFu];
                      atomicAdd(&acc[(int)((r >> 16) & 127u) * 64 + c], v * Wl[(int)(r >> 23) * 64 + c]); }
        if (ne > 2) { const unsigned r = recs[e0 + 2]; const float v = s1[r & 0xFFFFu];
                      atomicAdd(&acc[(int)((r >> 16) & 127u) * 64 + c], v * Wl[(int)(r >> 23) * 64 + c]); }
        if (ne > 3) { const unsigned r = recs[e0 + 3]; const float v = s1[r & 0xFFFFu];
                      atomicAdd(&acc[(int)((r >> 16) & 127u) * 64 + c], v * Wl[(int)(r >> 23) * 64 + c]); }
    }
    __syncthreads();

    const int base = p * 128;
    for (int i = tid; i < 128 * 16; i += 256) {
        const int row = base + (i >> 4);
        if (row < Nout)
            *(float4*)&outb[(size_t)row * 64 + (i & 15) * 4] = *(const float4*)&acc[i * 4];
    }
}

// ===========================================================================
// Fallback scatter conv (previously harness-verified path)
// ===========================================================================
template<int CIN>
__global__ __launch_bounds__(256) void conv_scatter(
    const float* __restrict__ x, const float* __restrict__ W,
    const int* __restrict__ src, const int* __restrict__ dst,
    float* __restrict__ acc, int E)
{
    __shared__ float Wl[CIN * 64];
    __shared__ float xl[4][4 * CIN];
    const int k   = blockIdx.y;
    const int tid = threadIdx.x;
    const int w   = tid >> 6;
    const int c   = tid & 63;

    const float* Wk = W + (size_t)k * (CIN * 64);
    for (int i = tid * 4; i < CIN * 64; i += 256 * 4)
        *(float4*)&Wl[i] = *(const float4*)&Wk[i];
    __syncthreads();

    const int* srcK = src + (size_t)k * E;
    const int* dstK = dst + (size_t)k * E;
    float* xw = xl[w];

    for (int e0 = blockIdx.x * 16 + w * 4; e0 < E; e0 += gridDim.x * 16) {
        const int ne = min(4, E - e0);
        for (int j = 0; j < ne; ++j) {
            const int s = srcK[e0 + j];
            #pragma unroll
            for (int h = 0; h < CIN / 64; ++h)
                xw[j * CIN + h * 64 + c] = x[(size_t)s * CIN + h * 64 + c];
        }
        __builtin_amdgcn_wave_barrier();

        float a0 = 0.f, a1 = 0.f, a2 = 0.f, a3 = 0.f;
        #pragma unroll 4
        for (int i = 0; i < CIN; i += 4) {
            const float4 x0 = *(const float4*)&xw[0 * CIN + i];
            const float4 x1 = *(const float4*)&xw[1 * CIN + i];
            const float4 x2 = *(const float4*)&xw[2 * CIN + i];
            const float4 x3 = *(const float4*)&xw[3 * CIN + i];
            const float w0 = Wl[(i + 0) * 64 + c];
            const float w1 = Wl[(i + 1) * 64 + c];
            const float w2 = Wl[(i + 2) * 64 + c];
            const float w3 = Wl[(i + 3) * 64 + c];
            a0 = fmaf(x0.w, w3, fmaf(x0.z, w2, fmaf(x0.y, w1, fmaf(x0.x, w0, a0))));
            a1 = fmaf(x1.w, w3, fmaf(x1.z, w2, fmaf(x1.y, w1, fmaf(x1.x, w0, a1))));
            a2 = fmaf(x2.w, w3, fmaf(x2.z, w2, fmaf(x2.y, w1, fmaf(x2.x, w0, a2))));
            a3 = fmaf(x3.w, w3, fmaf(x3.z, w2, fmaf(x3.y, w1, fmaf(x3.x, w0, a3))));
        }
        __builtin_amdgcn_wave_barrier();

        if (ne > 0) { const int d = dstK[e0 + 0]; atomicAdd(&acc[(size_t)d * 64 + c], a0); }
        if (ne > 1) { const int d = dstK[e0 + 1]; atomicAdd(&acc[(size_t)d * 64 + c], a1); }
        if (ne > 2) { const int d = dstK[e0 + 2]; atomicAdd(&acc[(size_t)d * 64 + c], a2); }
        if (ne > 3) { const int d = dstK[e0 + 3]; atomicAdd(&acc[(size_t)d * 64 + c], a3); }
    }
}

__global__ __launch_bounds__(256) void conv_up_kernel(
    const float* __restrict__ s1, const float* __restrict__ Wup,
    const int* __restrict__ gsrc, const int* __restrict__ sdst,
    float* __restrict__ out, int E)
{
    const int k = blockIdx.y;
    const int c = threadIdx.x & 63;
    const int w = threadIdx.x >> 6;
    const float wv = Wup[k * 64 + c];
    for (int e = blockIdx.x * 4 + w; e < E; e += gridDim.x * 4) {
        const float val = s1[gsrc[(size_t)k * E + e]];
        const int   di  = sdst[(size_t)k * E + e];
        atomicAdd(&out[(size_t)di * 64 + c], val * wv);
    }
}

// ---------------------------------------------------------------------------
// Cout=1 conv: acc1[dst] += dot(s[src,:64], W_sum[k,:,0]). Thread-per-edge.
// ---------------------------------------------------------------------------
__global__ __launch_bounds__(256) void conv_sum_kernel(
    const float* __restrict__ s, const float* __restrict__ Wsum,
    const int* __restrict__ src, const int* __restrict__ dst,
    float* __restrict__ acc1, int E)
{
    const int k = blockIdx.y;
    __shared__ float Wl[64];
    if (threadIdx.x < 64) Wl[threadIdx.x] = Wsum[k * 64 + threadIdx.x];
    __syncthreads();
    for (int e = blockIdx.x * 256 + threadIdx.x; e < E; e += gridDim.x * 256) {
        const int si = src[(size_t)k * E + e];
        const float4* row = (const float4*)(s + (size_t)si * 64);
        float acc = 0.f;
        #pragma unroll
        for (int q = 0; q < 16; ++q) {
            const float4 v = row[q];
            acc = fmaf(v.x, Wl[q * 4 + 0], acc);
            acc = fmaf(v.y, Wl[q * 4 + 1], acc);
            acc = fmaf(v.z, Wl[q * 4 + 2], acc);
            acc = fmaf(v.w, Wl[q * 4 + 3], acc);
        }
        atomicAdd(&acc1[dst[(size_t)k * E + e]], acc);
    }
}

// ---------------------------------------------------------------------------
__global__ __launch_bounds__(256) void stats64(
    const float* __restrict__ x, int N, float* __restrict__ st)
{
    const int c  = threadIdx.x & 63;
    const int rg = threadIdx.x >> 6;
    float s = 0.f, q = 0.f;
    for (int r = blockIdx.x * 4 + rg; r < N; r += gridDim.x * 4) {
        const float v = x[(size_t)r * 64 + c];
        s += v;
        q = fmaf(v, v, q);
    }
    __shared__ float ls[256], lq[256];
    ls[threadIdx.x] = s; lq[threadIdx.x] = q;
    __syncthreads();
    if (threadIdx.x < 64) {
        s = ls[c] + ls[64 + c] + ls[128 + c] + ls[192 + c];
        q = lq[c] + lq[64 + c] + lq[128 + c] + lq[192 + c];
        atomicAdd(&st[c], s);
        atomicAdd(&st[64 + c], q);
    }
}

__global__ __launch_bounds__(256) void stats1(
    const float* __restrict__ x, int N, float* __restrict__ st)
{
    float s = 0.f, q = 0.f;
    for (int i = blockIdx.x * 256 + threadIdx.x; i < N; i += gridDim.x * 256) {
        const float v = x[i];
        s += v;
        q = fmaf(v, v, q);
    }
    __shared__ float ls[256], lq[256];
    ls[threadIdx.x] = s; lq[threadIdx.x] = q;
    __syncthreads();
    for (int off = 128; off > 0; off >>= 1) {
        if (threadIdx.x < off) {
            ls[threadIdx.x] += ls[threadIdx.x + off];
            lq[threadIdx.x] += lq[threadIdx.x + off];
        }
        __syncthreads();
    }
    if (threadIdx.x == 0) { atomicAdd(&st[0], ls[0]); atomicAdd(&st[1], lq[0]); }
}

// ---------------------------------------------------------------------------
template<int ACT>
__global__ __launch_bounds__(256) void apply_bn(
    float* __restrict__ x, const float* __restrict__ st, int N, float invN,
    const float* __restrict__ gam, const float* __restrict__ bet,
    const float* __restrict__ add)
{
    __shared__ float sc[64], sh[64];
    if (threadIdx.x < 64) {
        const int c = threadIdx.x;
        const float m = st[c] * invN;
        const float v = st[64 + c] * invN - m * m;
        const float s = rsqrtf(v + EPS) * gam[c];
        sc[c] = s;
        sh[c] = bet[c] - m * s;
    }
    __syncthreads();
    const size_t n = (size_t)N * 64;
    for (size_t i = (size_t)blockIdx.x * 256 + threadIdx.x; i < n;
         i += (size_t)gridDim.x * 256) {
        const int c = (int)(i & 63);
        float y = fmaf(x[i], sc[c], sh[c]);
        if (ACT == 0) y = (y >= 0.f) ? y : SLOPE * y;
        else          y = 1.f / (1.f + __expf(-y));
        if (add) y += add[i];
        x[i] = y;
    }
}

__global__ __launch_bounds__(256) void apply_bn1(
    float* __restrict__ x, const float* __restrict__ st, int N, float invN,
    const float* __restrict__ gam, const float* __restrict__ bet)
{
    const float m  = st[0] * invN;
    const float v  = st[1] * invN - m * m;
    const float s  = rsqrtf(v + EPS) * gam[0];
    const float sh = bet[0] - m * s;
    for (int i = blockIdx.x * 256 + threadIdx.x; i < N; i += gridDim.x * 256) {
        const float y = fmaf(x[i], s, sh);
        x[i] = (y >= 0.f) ? y : SLOPE * y;
    }
}

// ---------------------------------------------------------------------------
extern "C" void kernel_launch(void* const* d_in, const int* in_sizes, int n_in,
                              void* d_out, int out_size, void* d_ws, size_t ws_size,
                              hipStream_t stream)
{
    const float* gate     = (const float*)d_in[0];
    const float* shortcut = (const float*)d_in[1];
    const int*   src_down = (const int*)d_in[2];
    const int*   dst_down = (const int*)d_in[3];
    const int*   src_g    = (const int*)d_in[4];
    const int*   dst_g    = (const int*)d_in[5];
    const float* W_sc     = (const float*)d_in[6];
    const float* W_g      = (const float*)d_in[8];
    const float* W_gu     = (const float*)d_in[10];
    const float* W_sum    = (const float*)d_in[12];
    const float* W_up     = (const float*)d_in[13];
    const float* gam_sc   = (const float*)d_in[15];
    const float* bet_sc   = (const float*)d_in[16];
    const float* gam_g    = (const float*)d_in[17];
    const float* bet_g    = (const float*)d_in[18];
    const float* gam_gu   = (const float*)d_in[19];
    const float* bet_gu   = (const float*)d_in[20];
    const float* gam_sum  = (const float*)d_in[21];
    const float* bet_sum  = (const float*)d_in[22];
    const float* gam_up   = (const float*)d_in[23];
    const float* bet_up   = (const float*)d_in[24];

    const int K   = 27;
    const int Nc  = in_sizes[0] / 128;   // 60000
    const int Nf  = in_sizes[1] / 64;    // 200000
    const int Ekd = in_sizes[2] / K;     // 40000
    const int Ekg = in_sizes[4] / K;     // 25000

    const int SHC = 6,  RC = 64;         // coarse range: 64 rows
    const int SHF = 7,  RF = 128;        // fine   range: 128 rows
    const int NRC = (Nc + RC - 1) / RC;  // 938
    const int NRF = (Nf + RF - 1) / RF;  // 1563
    const int NBC = NRC * K;
    const int NBF = NRF;

    float* A  = (float*)d_ws;            // theta
    float* B  = A + (size_t)Nc * 64;     // phi
    float* C  = B + (size_t)Nc * 64;     // s
    float* D  = C + (size_t)Nc * 64;     // s1 (Nc floats)
    float* ST = D + Nc;                  // stats: 640 floats
    float* out = (float*)d_out;
    const dim3 blk(256);

    // ---- workspace budget check: sort buffers live after ST ----
    const size_t intsNeeded =
        (size_t)(3 * NBC + NBF)            // cnt
      + (size_t)(3 * (NBC + 1) + NBF + 1)  // offs
      + (size_t)(3 * NBC + NBF)            // cur
      + 2 * (size_t)K * Ekd + 2 * (size_t)K * Ekg;  // recs
    const size_t bytesNeeded =
        ((size_t)Nc * 64 * 3 + Nc + 640) * sizeof(float) + intsNeeded * sizeof(int);

    if (bytesNeeded + 1024 <= ws_size) {
        // ================= sorted gather path =================
        int* cnt1 = (int*)(ST + 640);
        int* cnt2 = cnt1 + NBC;
        int* cnt3 = cnt2 + NBC;
        int* cnt4 = cnt3 + NBC;
        int* off1 = cnt4 + NBF;
        int* off2 = off1 + NBC + 1;
        int* off3 = off2 + NBC + 1;
        int* off4 = off3 + NBC + 1;
        int* cur1 = off4 + NBF + 1;
        int* cur2 = cur1 + NBC;
        int* cur3 = cur2 + NBC;
        int* cur4 = cur3 + NBC;
        unsigned* rec1 = (unsigned*)(cur4 + NBF);
        unsigned* rec2 = rec1 + (size_t)K * Ekd;
        unsigned* rec3 = rec2 + (size_t)K * Ekg;
        unsigned* rec4 = rec3 + (size_t)K * Ekg;

        hipMemsetAsync(cnt1, 0, (size_t)(3 * NBC + NBF) * sizeof(int), stream);
        hipMemsetAsync(D, 0, (size_t)(Nc + 640) * sizeof(float), stream);

        const dim3 eg(64, K);
        hist_kernel<1><<<eg, blk, 0, stream>>>(dst_down, Ekd, SHC, cnt1);
        hist_kernel<1><<<eg, blk, 0, stream>>>(dst_g,    Ekg, SHC, cnt2);
        hist_kernel<1><<<eg, blk, 0, stream>>>(src_g,    Ekg, SHC, cnt3);
        hist_kernel<0><<<eg, blk, 0, stream>>>(src_down, Ekd, SHF, cnt4);
        scan_kernel<<<1, 1024, 0, stream>>>(cnt1, NBC, off1, cur1);
        scan_kernel<<<1, 1024, 0, stream>>>(cnt2, NBC, off2, cur2);
        scan_kernel<<<1, 1024, 0, stream>>>(cnt3, NBC, off3, cur3);
        scan_kernel<<<1, 1024, 0, stream>>>(cnt4, NBF, off4, cur4);
        bucket_kernel<1><<<eg, blk, 0, stream>>>(src_down, dst_down, Ekd, SHC, 24, 0,  cur1, rec1);
        bucket_kernel<1><<<eg, blk, 0, stream>>>(src_g,    dst_g,    Ekg, SHC, 24, 0,  cur2, rec2);
        bucket_kernel<1><<<eg, blk, 0, stream>>>(dst_g,    src_g,    Ekg, SHC, 24, 0,  cur3, rec3);
        bucket_kernel<0><<<eg, blk, 0, stream>>>(dst_down, src_down, Ekd, SHF, 16, 23, cur4, rec4);

        conv_gather<64><<<NRC, blk, 0, stream>>>(shortcut, W_sc, rec1, off1, A, Nc);
        conv_gather<128><<<NRC, blk, 0, stream>>>(gate, W_g, rec2, off2, B, Nc);

        stats64<<<256, blk, 0, stream>>>(A, Nc, ST + 0);
        stats64<<<256, blk, 0, stream>>>(B, Nc, ST + 128);
        apply_bn<0><<<1024, blk, 0, stream>>>(A, ST + 0,   Nc, 1.0f / Nc, gam_sc, bet_sc, nullptr);
        apply_bn<0><<<1024, blk, 0, stream>>>(B, ST + 128, Nc, 1.0f / Nc, gam_g,  bet_g,  nullptr);

        conv_gather<64><<<NRC, blk, 0, stream>>>(B, W_gu, rec3, off3, C, Nc);
        stats64<<<256, blk, 0, stream>>>(C, Nc, ST + 256);
        apply_bn<0><<<1024, blk, 0, stream>>>(C, ST + 256, Nc, 1.0f / Nc, gam_gu, bet_gu, A);

        conv_sum_kernel<<<dim3(32, K), blk, 0, stream>>>(C, W_sum, src_g, dst_g, D, Ekg);
        stats1<<<256, blk, 0, stream>>>(D, Nc, ST + 384);
        apply_bn1<<<256, blk, 0, stream>>>(D, ST + 384, Nc, 1.0f / Nc, gam_sum, bet_sum);

        conv_up_gather<<<NRF, blk, 0, stream>>>(D, W_up, rec4, off4, out, Nf);
        stats64<<<512, blk, 0, stream>>>(out, Nf, ST + 512);
        apply_bn<1><<<2048, blk, 0, stream>>>(out, ST + 512, Nf, 1.0f / Nf, gam_up, bet_up, nullptr);
    } else {
        // ================= fallback: verified scatter path =================
        const size_t zeroBytes = ((size_t)Nc * 64 * 3 + (size_t)Nc + 640) * sizeof(float);
        hipMemsetAsync(d_ws, 0, zeroBytes, stream);
        hipMemsetAsync(d_out, 0, (size_t)out_size * sizeof(float), stream);

        conv_scatter<64><<<dim3(64, K), blk, 0, stream>>>(shortcut, W_sc, src_down, dst_down, A, Ekd);
        conv_scatter<128><<<dim3(64, K), blk, 0, stream>>>(gate, W_g, src_g, dst_g, B, Ekg);

        stats64<<<256, blk, 0, stream>>>(A, Nc, ST + 0);
        stats64<<<256, blk, 0, stream>>>(B, Nc, ST + 128);
        apply_bn<0><<<1024, blk, 0, stream>>>(A, ST + 0,   Nc, 1.0f / Nc, gam_sc, bet_sc, nullptr);
        apply_bn<0><<<1024, blk, 0, stream>>>(B, ST + 128, Nc, 1.0f / Nc, gam_g,  bet_g,  nullptr);

        conv_scatter<64><<<dim3(64, K), blk, 0, stream>>>(B, W_gu, dst_g, src_g, C, Ekg);
        stats64<<<256, blk, 0, stream>>>(C, Nc, ST + 256);
        apply_bn<0><<<1024, blk, 0, stream>>>(C, ST + 256, Nc, 1.0f / Nc, gam_gu, bet_gu, A);

        conv_sum_kernel<<<dim3(32, K), blk, 0, stream>>>(C, W_sum, src_g, dst_g, D, Ekg);
        stats1<<<256, blk, 0, stream>>>(D, Nc, ST + 384);
        apply_bn1<<<256, blk, 0, stream>>>(D, ST + 384, Nc, 1.0f / Nc, gam_sum, bet_sum);

        conv_up_kernel<<<dim3(64, K), blk, 0, stream>>>(D, W_up, dst_down, src_down, out, Ekd);
        stats64<<<512, blk, 0, stream>>>(out, Nf, ST + 512);
        apply_bn<1><<<2048, blk, 0, stream>>>(out, ST + 512, Nf, 1.0f / Nf, gam_up, bet_up, nullptr);
    }
}

// Round 3
// 3239.168 us; speedup vs baseline: 1.0748x; 1.0748x over previous
//
#include <hip/hip_runtime.h>

#define EPS 1e-5f
#define SLOPE 0.01f

// ===========================================================================
// Preprocessing: counting-sort edges by (output-range [, k]).
// S1: down pairs   key=(dst_down>>6)*27+k  rec = src | (dst&63)<<24
// S2: g pairs      key=(dst_g>>6)*27+k     rec = src | (dst&63)<<24
// S3: g transposed key=(src_g>>6)*27+k     rec = dst | (src&63)<<24
// S4: down transposed (for conv_up) key=src_down>>7
//     rec = dst_down | (src_down&127)<<16 | k<<23
// ===========================================================================
template<int WITHK>
__global__ __launch_bounds__(256) void hist_kernel(
    const int* __restrict__ scat, int E, int SH, int* __restrict__ cnt)
{
    const int k = blockIdx.y;
    const int* s = scat + (size_t)k * E;
    for (int e = blockIdx.x * 256 + threadIdx.x; e < E; e += gridDim.x * 256) {
        int key = s[e] >> SH;
        if (WITHK) key = key * 27 + k;
        atomicAdd(&cnt[key], 1);
    }
}

__global__ __launch_bounds__(1024) void scan_kernel(
    const int* __restrict__ cnt, int n, int* __restrict__ offs, int* __restrict__ cur)
{
    __shared__ int part[1024];
    const int tid = threadIdx.x;
    const int chunk = (n + 1023) >> 10;
    const int lo = tid * chunk, hi = min(n, lo + chunk);
    int s = 0;
    for (int i = lo; i < hi; ++i) s += cnt[i];
    part[tid] = s;
    __syncthreads();
    for (int d = 1; d < 1024; d <<= 1) {
        const int t = (tid >= d) ? part[tid - d] : 0;
        __syncthreads();
        part[tid] += t;
        __syncthreads();
    }
    int run = part[tid] - s;                 // exclusive prefix of this chunk
    for (int i = lo; i < hi; ++i) {
        const int cv = cnt[i];
        offs[i] = run; cur[i] = run; run += cv;
    }
    if (tid == 1023) offs[n] = run;          // total
}

template<int WITHK>
__global__ __launch_bounds__(256) void bucket_kernel(
    const int* __restrict__ gat, const int* __restrict__ scat, int E, int SH,
    int packSH, int kSH, int* __restrict__ cur, unsigned* __restrict__ recs)
{
    const int k = blockIdx.y;
    const int* g = gat + (size_t)k * E;
    const int* d = scat + (size_t)k * E;
    for (int e = blockIdx.x * 256 + threadIdx.x; e < E; e += gridDim.x * 256) {
        const int dv = d[e];
        int key = dv >> SH;
        if (WITHK) key = key * 27 + k;
        unsigned rec = (unsigned)g[e] | ((unsigned)(dv & ((1 << SH) - 1)) << packSH);
        if (!WITHK) rec |= (unsigned)k << kSH;
        const int pos = atomicAdd(&cur[key], 1);
        recs[pos] = rec;
    }
}

// ===========================================================================
// Register-W gather conv. Block owns 64 output rows in LDS; wave w owns
// k in {w, w+4, ...} so waves run barrier-free through their bins. W column
// for lane c lives in 64 VGPRs (per 64-input-channel chunk). Cross-wave
// accumulation via LDS atomicAdd (lane=channel: conflict-free). Fused
// per-channel sum/sumsq epilogue (rows >= Nout stay zero -> contribute 0).
// ===========================================================================
template<int CHUNKS>
__global__ __launch_bounds__(256) void conv_rw(
    const float* __restrict__ x, const float* __restrict__ W,
    const unsigned* __restrict__ recs, const int* __restrict__ offs,
    float* __restrict__ outb, int Nout, float* __restrict__ st)
{
    constexpr int CIN = CHUNKS * 64;
    __shared__ float acc[64 * 64];     // 16 KB
    __shared__ float xs[4][4 * 64];    // 4 KB  per-wave 4 edges x 64-ch chunk
    __shared__ float red[512];         // 2 KB  stats reduction
    const int p   = blockIdx.x;
    const int tid = threadIdx.x;
    const int w   = tid >> 6;
    const int c   = tid & 63;

    const float4 z = {0.f, 0.f, 0.f, 0.f};
    for (int i = tid * 4; i < 64 * 64; i += 1024) *(float4*)&acc[i] = z;
    __syncthreads();

    float* xw = xs[w];
    const int* offp = offs + p * 27;

    for (int k = w; k < 27; k += 4) {
        const int lo = offp[k], hi = offp[k + 1];
        if (lo >= hi) continue;
        for (int ch = 0; ch < CHUNKS; ++ch) {
            // W[k] chunk column for this lane: wr[i] = W[k][ch*64+i][c]
            const float* Wc = W + ((size_t)k * CIN + ch * 64) * 64 + c;
            float wr[64];
            #pragma unroll
            for (int i = 0; i < 64; ++i) wr[i] = Wc[i * 64];

            const int xoff = ch * 64;
            for (int e0 = lo; e0 < hi; e0 += 4) {
                const int ne = hi - e0;
                const unsigned r0 = recs[e0];
                const unsigned r1 = recs[min(e0 + 1, hi - 1)];
                const unsigned r2 = recs[min(e0 + 2, hi - 1)];
                const unsigned r3 = recs[min(e0 + 3, hi - 1)];
                xw[0 * 64 + c] = x[(size_t)(r0 & 0xFFFFFFu) * CIN + xoff + c];
                xw[1 * 64 + c] = x[(size_t)(r1 & 0xFFFFFFu) * CIN + xoff + c];
                xw[2 * 64 + c] = x[(size_t)(r2 & 0xFFFFFFu) * CIN + xoff + c];
                xw[3 * 64 + c] = x[(size_t)(r3 & 0xFFFFFFu) * CIN + xoff + c];
                __builtin_amdgcn_wave_barrier();

                float a0 = 0.f, a1 = 0.f, a2 = 0.f, a3 = 0.f;
                #pragma unroll
                for (int i = 0; i < 64; i += 4) {
                    const float4 x0 = *(const float4*)&xw[0 * 64 + i];
                    const float4 x1 = *(const float4*)&xw[1 * 64 + i];
                    const float4 x2 = *(const float4*)&xw[2 * 64 + i];
                    const float4 x3 = *(const float4*)&xw[3 * 64 + i];
                    a0 = fmaf(x0.w, wr[i + 3], fmaf(x0.z, wr[i + 2], fmaf(x0.y, wr[i + 1], fmaf(x0.x, wr[i + 0], a0))));
                    a1 = fmaf(x1.w, wr[i + 3], fmaf(x1.z, wr[i + 2], fmaf(x1.y, wr[i + 1], fmaf(x1.x, wr[i + 0], a1))));
                    a2 = fmaf(x2.w, wr[i + 3], fmaf(x2.z, wr[i + 2], fmaf(x2.y, wr[i + 1], fmaf(x2.x, wr[i + 0], a2))));
                    a3 = fmaf(x3.w, wr[i + 3], fmaf(x3.z, wr[i + 2], fmaf(x3.y, wr[i + 1], fmaf(x3.x, wr[i + 0], a3))));
                }
                __builtin_amdgcn_wave_barrier();

                atomicAdd(&acc[(int)(r0 >> 24) * 64 + c], a0);
                if (ne > 1) atomicAdd(&acc[(int)(r1 >> 24) * 64 + c], a1);
                if (ne > 2) atomicAdd(&acc[(int)(r2 >> 24) * 64 + c], a2);
                if (ne > 3) atomicAdd(&acc[(int)(r3 >> 24) * 64 + c], a3);
            }
        }
    }
    __syncthreads();

    const int base = p * 64;
    for (int i = tid; i < 64 * 16; i += 256) {
        const int row = base + (i >> 4);
        if (row < Nout)
            *(float4*)&outb[(size_t)row * 64 + (i & 15) * 4] = *(const float4*)&acc[i * 4];
    }

    // fused per-channel stats over this block's 64 rows
    float s = 0.f, q = 0.f;
    #pragma unroll
    for (int rr = 0; rr < 16; ++rr) {
        const float v = acc[(w * 16 + rr) * 64 + c];
        s += v;
        q = fmaf(v, v, q);
    }
    red[tid] = s; red[256 + tid] = q;
    __syncthreads();
    if (tid < 64) {
        atomicAdd(&st[c],      red[c] + red[64 + c] + red[128 + c] + red[192 + c]);
        atomicAdd(&st[64 + c], red[256 + c] + red[320 + c] + red[384 + c] + red[448 + c]);
    }
}

// ---------------------------------------------------------------------------
// Cin=1 up-conv, gather-style: block owns 128 fine rows; all of W_up in LDS.
// Fused per-channel stats epilogue.
// ---------------------------------------------------------------------------
__global__ __launch_bounds__(256) void conv_up_gather(
    const float* __restrict__ s1, const float* __restrict__ Wup,
    const unsigned* __restrict__ recs, const int* __restrict__ offs,
    float* __restrict__ outb, int Nout, float* __restrict__ st)
{
    __shared__ float acc[128 * 64];          // 32 KB
    __shared__ float Wl[27 * 64];            // 6.9 KB (reused as stats scratch)
    const int p   = blockIdx.x;
    const int tid = threadIdx.x;
    const int w   = tid >> 6;
    const int c   = tid & 63;

    const float4 z = {0.f, 0.f, 0.f, 0.f};
    for (int i = tid * 4; i < 128 * 64; i += 1024) *(float4*)&acc[i] = z;
    for (int i = tid; i < 27 * 64; i += 256) Wl[i] = Wup[i];
    __syncthreads();

    const int lo = offs[p], hi = offs[p + 1];
    for (int e0 = lo + w * 4; e0 < hi; e0 += 16) {
        const int ne = min(4, hi - e0);
        if (ne > 0) { const unsigned r = recs[e0 + 0]; const float v = s1[r & 0xFFFFu];
                      atomicAdd(&acc[(int)((r >> 16) & 127u) * 64 + c], v * Wl[(int)(r >> 23) * 64 + c]); }
        if (ne > 1) { const unsigned r = recs[e0 + 1]; const float v = s1[r & 0xFFFFu];
                      atomicAdd(&acc[(int)((r >> 16) & 127u) * 64 + c], v * Wl[(int)(r >> 23) * 64 + c]); }
        if (ne > 2) { const unsigned r = recs[e0 + 2]; const float v = s1[r & 0xFFFFu];
                      atomicAdd(&acc[(int)((r >> 16) & 127u) * 64 + c], v * Wl[(int)(r >> 23) * 64 + c]); }
        if (ne > 3) { const unsigned r = recs[e0 + 3]; const float v = s1[r & 0xFFFFu];
                      atomicAdd(&acc[(int)((r >> 16) & 127u) * 64 + c], v * Wl[(int)(r >> 23) * 64 + c]); }
    }
    __syncthreads();

    const int base = p * 128;
    for (int i = tid; i < 128 * 16; i += 256) {
        const int row = base + (i >> 4);
        if (row < Nout)
            *(float4*)&outb[(size_t)row * 64 + (i & 15) * 4] = *(const float4*)&acc[i * 4];
    }

    // fused stats: wave w covers rows w*32 .. w*32+31 (OOB rows are zero)
    float s = 0.f, q = 0.f;
    #pragma unroll
    for (int rr = 0; rr < 32; ++rr) {
        const float v = acc[(w * 32 + rr) * 64 + c];
        s += v;
        q = fmaf(v, v, q);
    }
    __syncthreads();
    Wl[tid] = s; Wl[256 + tid] = q;
    __syncthreads();
    if (tid < 64) {
        atomicAdd(&st[c],      Wl[c] + Wl[64 + c] + Wl[128 + c] + Wl[192 + c]);
        atomicAdd(&st[64 + c], Wl[256 + c] + Wl[320 + c] + Wl[384 + c] + Wl[448 + c]);
    }
}

// ---------------------------------------------------------------------------
// Cout=1 conv: acc1[dst] += dot(s[src,:64], W_sum[k,:,0]). Thread-per-edge.
// Atomic traffic only 2.7 MB -> scatter form is fine.
// ---------------------------------------------------------------------------
__global__ __launch_bounds__(256) void conv_sum_kernel(
    const float* __restrict__ s, const float* __restrict__ Wsum,
    const int* __restrict__ src, const int* __restrict__ dst,
    float* __restrict__ acc1, int E)
{
    const int k = blockIdx.y;
    __shared__ float Wl[64];
    if (threadIdx.x < 64) Wl[threadIdx.x] = Wsum[k * 64 + threadIdx.x];
    __syncthreads();
    for (int e = blockIdx.x * 256 + threadIdx.x; e < E; e += gridDim.x * 256) {
        const int si = src[(size_t)k * E + e];
        const float4* row = (const float4*)(s + (size_t)si * 64);
        float acc = 0.f;
        #pragma unroll
        for (int q = 0; q < 16; ++q) {
            const float4 v = row[q];
            acc = fmaf(v.x, Wl[q * 4 + 0], acc);
            acc = fmaf(v.y, Wl[q * 4 + 1], acc);
            acc = fmaf(v.z, Wl[q * 4 + 2], acc);
            acc = fmaf(v.w, Wl[q * 4 + 3], acc);
        }
        atomicAdd(&acc1[dst[(size_t)k * E + e]], acc);
    }
}

// ---------------------------------------------------------------------------
__global__ __launch_bounds__(256) void stats1(
    const float* __restrict__ x, int N, float* __restrict__ st)
{
    float s = 0.f, q = 0.f;
    for (int i = blockIdx.x * 256 + threadIdx.x; i < N; i += gridDim.x * 256) {
        const float v = x[i];
        s += v;
        q = fmaf(v, v, q);
    }
    __shared__ float ls[256], lq[256];
    ls[threadIdx.x] = s; lq[threadIdx.x] = q;
    __syncthreads();
    for (int off = 128; off > 0; off >>= 1) {
        if (threadIdx.x < off) {
            ls[threadIdx.x] += ls[threadIdx.x + off];
            lq[threadIdx.x] += lq[threadIdx.x + off];
        }
        __syncthreads();
    }
    if (threadIdx.x == 0) { atomicAdd(&st[0], ls[0]); atomicAdd(&st[1], lq[0]); }
}

// ---------------------------------------------------------------------------
// In-place BN + activation (ACT 0=LeakyReLU, 1=sigmoid), optional += add.
// ---------------------------------------------------------------------------
template<int ACT>
__global__ __launch_bounds__(256) void apply_bn(
    float* __restrict__ x, const float* __restrict__ st, int N, float invN,
    const float* __restrict__ gam, const float* __restrict__ bet,
    const float* __restrict__ add)
{
    __shared__ float sc[64], sh[64];
    if (threadIdx.x < 64) {
        const int c = threadIdx.x;
        const float m = st[c] * invN;
        const float v = st[64 + c] * invN - m * m;
        const float s = rsqrtf(v + EPS) * gam[c];
        sc[c] = s;
        sh[c] = bet[c] - m * s;
    }
    __syncthreads();
    const size_t n = (size_t)N * 64;
    for (size_t i = (size_t)blockIdx.x * 256 + threadIdx.x; i < n;
         i += (size_t)gridDim.x * 256) {
        const int c = (int)(i & 63);
        float y = fmaf(x[i], sc[c], sh[c]);
        if (ACT == 0) y = (y >= 0.f) ? y : SLOPE * y;
        else          y = 1.f / (1.f + __expf(-y));
        if (add) y += add[i];
        x[i] = y;
    }
}

__global__ __launch_bounds__(256) void apply_bn1(
    float* __restrict__ x, const float* __restrict__ st, int N, float invN,
    const float* __restrict__ gam, const float* __restrict__ bet)
{
    const float m  = st[0] * invN;
    const float v  = st[1] * invN - m * m;
    const float s  = rsqrtf(v + EPS) * gam[0];
    const float sh = bet[0] - m * s;
    for (int i = blockIdx.x * 256 + threadIdx.x; i < N; i += gridDim.x * 256) {
        const float y = fmaf(x[i], s, sh);
        x[i] = (y >= 0.f) ? y : SLOPE * y;
    }
}

// ---------------------------------------------------------------------------
extern "C" void kernel_launch(void* const* d_in, const int* in_sizes, int n_in,
                              void* d_out, int out_size, void* d_ws, size_t ws_size,
                              hipStream_t stream)
{
    const float* gate     = (const float*)d_in[0];
    const float* shortcut = (const float*)d_in[1];
    const int*   src_down = (const int*)d_in[2];
    const int*   dst_down = (const int*)d_in[3];
    const int*   src_g    = (const int*)d_in[4];
    const int*   dst_g    = (const int*)d_in[5];
    const float* W_sc     = (const float*)d_in[6];
    const float* W_g      = (const float*)d_in[8];
    const float* W_gu     = (const float*)d_in[10];
    const float* W_sum    = (const float*)d_in[12];
    const float* W_up     = (const float*)d_in[13];
    const float* gam_sc   = (const float*)d_in[15];
    const float* bet_sc   = (const float*)d_in[16];
    const float* gam_g    = (const float*)d_in[17];
    const float* bet_g    = (const float*)d_in[18];
    const float* gam_gu   = (const float*)d_in[19];
    const float* bet_gu   = (const float*)d_in[20];
    const float* gam_sum  = (const float*)d_in[21];
    const float* bet_sum  = (const float*)d_in[22];
    const float* gam_up   = (const float*)d_in[23];
    const float* bet_up   = (const float*)d_in[24];

    const int K   = 27;
    const int Nc  = in_sizes[0] / 128;   // 60000
    const int Nf  = in_sizes[1] / 64;    // 200000
    const int Ekd = in_sizes[2] / K;     // 40000
    const int Ekg = in_sizes[4] / K;     // 25000

    const int SHC = 6,  RC = 64;         // coarse range: 64 rows
    const int SHF = 7,  RF = 128;        // fine   range: 128 rows
    const int NRC = (Nc + RC - 1) / RC;  // 938
    const int NRF = (Nf + RF - 1) / RF;  // 1563
    const int NBC = NRC * K;
    const int NBF = NRF;

    float* A  = (float*)d_ws;            // theta
    float* B  = A + (size_t)Nc * 64;     // phi
    float* C  = B + (size_t)Nc * 64;     // s
    float* D  = C + (size_t)Nc * 64;     // s1 (Nc floats)
    float* ST = D + Nc;                  // stats: 640 floats
    int* cnt1 = (int*)(ST + 640);
    int* cnt2 = cnt1 + NBC;
    int* cnt3 = cnt2 + NBC;
    int* cnt4 = cnt3 + NBC;
    int* off1 = cnt4 + NBF;
    int* off2 = off1 + NBC + 1;
    int* off3 = off2 + NBC + 1;
    int* off4 = off3 + NBC + 1;
    int* cur1 = off4 + NBF + 1;
    int* cur2 = cur1 + NBC;
    int* cur3 = cur2 + NBC;
    int* cur4 = cur3 + NBC;
    unsigned* rec1 = (unsigned*)(cur4 + NBF);
    unsigned* rec2 = rec1 + (size_t)K * Ekd;
    unsigned* rec3 = rec2 + (size_t)K * Ekg;
    unsigned* rec4 = rec3 + (size_t)K * Ekg;

    hipMemsetAsync(cnt1, 0, (size_t)(3 * NBC + NBF) * sizeof(int), stream);
    hipMemsetAsync(D, 0, (size_t)(Nc + 640) * sizeof(float), stream);
    float* out = (float*)d_out;

    const dim3 blk(256);
    const dim3 eg(64, K);

    // ---- build sorted edge lists (counting sort by output range [,k]) ----
    hist_kernel<1><<<eg, blk, 0, stream>>>(dst_down, Ekd, SHC, cnt1);
    hist_kernel<1><<<eg, blk, 0, stream>>>(dst_g,    Ekg, SHC, cnt2);
    hist_kernel<1><<<eg, blk, 0, stream>>>(src_g,    Ekg, SHC, cnt3);
    hist_kernel<0><<<eg, blk, 0, stream>>>(src_down, Ekd, SHF, cnt4);
    scan_kernel<<<1, 1024, 0, stream>>>(cnt1, NBC, off1, cur1);
    scan_kernel<<<1, 1024, 0, stream>>>(cnt2, NBC, off2, cur2);
    scan_kernel<<<1, 1024, 0, stream>>>(cnt3, NBC, off3, cur3);
    scan_kernel<<<1, 1024, 0, stream>>>(cnt4, NBF, off4, cur4);
    bucket_kernel<1><<<eg, blk, 0, stream>>>(src_down, dst_down, Ekd, SHC, 24, 0,  cur1, rec1);
    bucket_kernel<1><<<eg, blk, 0, stream>>>(src_g,    dst_g,    Ekg, SHC, 24, 0,  cur2, rec2);
    bucket_kernel<1><<<eg, blk, 0, stream>>>(dst_g,    src_g,    Ekg, SHC, 24, 0,  cur3, rec3);
    bucket_kernel<0><<<eg, blk, 0, stream>>>(dst_down, src_down, Ekd, SHF, 16, 23, cur4, rec4);

    // theta = leaky(bn(sconv(shortcut, W_sc, src_down->dst_down)))
    conv_rw<1><<<NRC, blk, 0, stream>>>(shortcut, W_sc, rec1, off1, A, Nc, ST + 0);
    // phi_raw = sconv(gate, W_g, src_g->dst_g)
    conv_rw<2><<<NRC, blk, 0, stream>>>(gate, W_g, rec2, off2, B, Nc, ST + 128);

    apply_bn<0><<<1024, blk, 0, stream>>>(A, ST + 0,   Nc, 1.0f / Nc, gam_sc, bet_sc, nullptr);
    apply_bn<0><<<1024, blk, 0, stream>>>(B, ST + 128, Nc, 1.0f / Nc, gam_g,  bet_g,  nullptr);

    // phi = leaky(bn(sconv(phi, W_gu, dst_g->src_g)))  (transposed index pairs)
    conv_rw<1><<<NRC, blk, 0, stream>>>(B, W_gu, rec3, off3, C, Nc, ST + 256);
    // s = leaky(bn(C)) + theta
    apply_bn<0><<<1024, blk, 0, stream>>>(C, ST + 256, Nc, 1.0f / Nc, gam_gu, bet_gu, A);

    // s1 = leaky(bn(sconv(s, W_sum, src_g->dst_g)))   (Cout = 1)
    conv_sum_kernel<<<dim3(32, K), blk, 0, stream>>>(C, W_sum, src_g, dst_g, D, Ekg);
    stats1<<<256, blk, 0, stream>>>(D, Nc, ST + 384);
    apply_bn1<<<256, blk, 0, stream>>>(D, ST + 384, Nc, 1.0f / Nc, gam_sum, bet_sum);

    // out = sigmoid(bn(sconv(s1, W_up, dst_down->src_down)))  (Cin = 1, fine res)
    conv_up_gather<<<NRF, blk, 0, stream>>>(D, W_up, rec4, off4, out, Nf, ST + 512);
    apply_bn<1><<<2048, blk, 0, stream>>>(out, ST + 512, Nf, 1.0f / Nf, gam_up, bet_up, nullptr);
}